// Round 9
// baseline (17239.357 us; speedup 1.0000x reference)
//
#include <hip/hip_runtime.h>

// ---------------- problem constants ----------------
#define TT 100
#define NSTEP 8
__device__ __constant__ float kDT_SC = 1.0f / 24.0f;
#define HS (0.125f)

typedef float f4 __attribute__((ext_vector_type(4)));
typedef float f2 __attribute__((ext_vector_type(2)));

// ---------------- d_ws layout (floats) ----------------
#define OFF_WHH1T4   0         // [64][256][4]
#define OFF_WIH1T    65536     // [20][256]
#define OFF_WIH2AT   70656     // [8][256]
#define OFF_WIH2BT4  72704     // [64][256][4]
#define OFF_WHH2T4   138240    // [64][256][4]
#define OFF_OW1T4    203776    // [64][256][4]
#define OFF_IW1T4    269312    // [64][256][4]
#define OFF_FW1R     334848    // [64][256] row-major, zero-padded rows >= 50
#define OFF_FW2T4    351232    // [13][256][4]
#define OFF_B1C      364544    // [256] bih1+bhh1
#define OFF_B2C      364800    // [256] bih2+bhh2
#define WS_FLOATS    365056

// ---------------- LDS layout (floats) ----------------
#define L_FW2   0        // [13][256][4] staged fW2T4 = 13312
#define L_YCUR  13312    // 2 states * 272 (4 chunks of 68 = 64 data + 4 pad)
#define L_Z     13856    // 2 states * 64
#define L_PART  13984    // 2 * 256 cell partials
#define L_XA    14496    // 28
#define L_TR    14524    // 1
#define L_RED   14525    // 8
#define L_TOTAL 14533

__device__ __forceinline__ float fast_tanh(float v) {
    float e = __expf(2.0f * v);
    return 1.0f - 2.0f / (e + 1.0f);
}
__device__ __forceinline__ f2 vlo(f4 v) { return __builtin_shufflevector(v, v, 0, 1); }
__device__ __forceinline__ f2 vhi(f4 v) { return __builtin_shufflevector(v, v, 2, 3); }
// packed f32 fma (v_pk_fma_f32)
__device__ __forceinline__ void pkfma(f2& a, f2 w, f2 h) {
    a = __builtin_elementwise_fma(w, h, a);
}
__device__ __forceinline__ float rsum2(f2 a) { return a.x + a.y; }

// padded ycur indexing: state v has 4 chunks of 68 floats (64 data + 4 pad)
__device__ __forceinline__ int yoffF(int v, int j) { return v * 272 + (j >> 6) * 68 + (j & 63); }
__device__ __forceinline__ int yoff4(int v, int jb) { return v * 68 + (jb >> 4) * 17 + (jb & 15); }

// 16-lane allreduce via DPP rotate-add (row_ror:1,2,4,8)
template <int CTRL>
__device__ __forceinline__ float dpp_rr_add(float v) {
    int r = __builtin_amdgcn_update_dpp(0, __float_as_int(v), CTRL, 0xF, 0xF, false);
    return v + __int_as_float(r);
}
__device__ __forceinline__ float allreduce16(float v) {
    v = dpp_rr_add<0x121>(v);
    v = dpp_rr_add<0x122>(v);
    v = dpp_rr_add<0x124>(v);
    v = dpp_rr_add<0x128>(v);
    return v;
}

// ================= setup: repack weights into d_ws =================
__global__ void codernn_setup(const float* __restrict__ Wih1, const float* __restrict__ Whh1,
                              const float* __restrict__ bih1, const float* __restrict__ bhh1,
                              const float* __restrict__ Wih2, const float* __restrict__ Whh2,
                              const float* __restrict__ bih2, const float* __restrict__ bhh2,
                              const float* __restrict__ oW1, const float* __restrict__ iW1,
                              const float* __restrict__ fW1, const float* __restrict__ fW2,
                              float* __restrict__ ws) {
    int e = blockIdx.x * 256 + threadIdx.x;
    if (e >= WS_FLOATS) return;
    float v;
    if (e < OFF_WIH1T) {                 // Whh1T4
        int q = e; int jb = q >> 10, i = (q >> 2) & 255, dj = q & 3;
        v = Whh1[i * 256 + jb * 4 + dj];
    } else if (e < OFF_WIH2AT) {         // Wih1T [20][256]
        int q = e - OFF_WIH1T; int j = q >> 8, i = q & 255;
        v = (j < 19) ? Wih1[i * 19 + j] : 0.0f;
    } else if (e < OFF_WIH2BT4) {        // Wih2aT [8][256] (insulin cols 0..4)
        int q = e - OFF_WIH2AT; int j = q >> 8, i = q & 255;
        v = (j < 5) ? Wih2[i * 261 + j] : 0.0f;
    } else if (e < OFF_WHH2T4) {         // Wih2bT4 (cols 5..260)
        int q = e - OFF_WIH2BT4; int jb = q >> 10, i = (q >> 2) & 255, dj = q & 3;
        v = Wih2[i * 261 + 5 + jb * 4 + dj];
    } else if (e < OFF_OW1T4) {          // Whh2T4
        int q = e - OFF_WHH2T4; int jb = q >> 10, i = (q >> 2) & 255, dj = q & 3;
        v = Whh2[i * 256 + jb * 4 + dj];
    } else if (e < OFF_IW1T4) {          // oW1T4
        int q = e - OFF_OW1T4; int jb = q >> 10, i = (q >> 2) & 255, dj = q & 3;
        v = oW1[i * 256 + jb * 4 + dj];
    } else if (e < OFF_FW1R) {           // iW1T4
        int q = e - OFF_IW1T4; int jb = q >> 10, i = (q >> 2) & 255, dj = q & 3;
        v = iW1[i * 256 + jb * 4 + dj];
    } else if (e < OFF_FW2T4) {          // FW1R [64][256] row-major, zero-pad k>=50
        int q = e - OFF_FW1R; int k = q >> 8, j = q & 255;
        v = (k < 50) ? fW1[k * 256 + j] : 0.0f;
    } else if (e < OFF_B1C) {            // fW2T4 [13][256][4]: (kb*256+i)*4+dk = fW2[i][4kb+dk]
        int q = e - OFF_FW2T4; int kb = q >> 10, i = (q >> 2) & 255, dk = q & 3;
        int k = kb * 4 + dk;
        v = (k < 50) ? fW2[i * 50 + k] : 0.0f;
    } else if (e < OFF_B2C) {
        int q = e - OFF_B1C; v = bih1[q] + bhh1[q];
    } else {
        int q = e - OFF_B2C; v = bih2[q] + bhh2[q];
    }
    ws[e] = v;
}

// ================= main kernel =================
// 512 threads per batch element; 512 blocks = 2 blocks/CU = 16 waves/CU.
// sh = tid>>8 splits roles; thread (i,sh) owns comp i of state sh.
__global__ __launch_bounds__(512, 4) void codernn_main(
    const float* __restrict__ dt, const float* __restrict__ x,
    const float* __restrict__ ws,
    const float* __restrict__ ob1, const float* __restrict__ oW2, const float* __restrict__ ob2,
    const float* __restrict__ ib1, const float* __restrict__ iW2, const float* __restrict__ ib2,
    const float* __restrict__ fb1, const float* __restrict__ fb2,
    float* __restrict__ out) {
    __shared__ float sm[L_TOTAL];
    const int tid = threadIdx.x;
    const int i = tid & 255;         // owned H component
    const int sh = tid >> 8;         // role / owned state
    const int bg = blockIdx.x;
    const int lane = tid & 63, wv = tid >> 6;

    // stage fW2T4 into LDS; zero ycur (incl. pads)
    for (int idx = tid; idx < 13312; idx += 512) sm[L_FW2 + idx] = ws[OFF_FW2T4 + idx];
    for (int idx = tid; idx < 544; idx += 512) sm[L_YCUR + idx] = 0.0f;

    // per-thread constants
    const float b1ci = ws[OFF_B1C + i];
    const float b2ci = ws[OFF_B2C + i];
    const float fb2i = fb2[i];
    const float W2sel = sh ? iW2[i] : oW2[i];
    const float b1sel = sh ? ib1[i] : ob1[i];
    const float ob2s = ob2[0], ib2s = ib2[0];

    // ---- z-phase role: (kg in 32, p16 in 16); rows 2kg, 2kg+1 ----
    const int kg = tid >> 4;
    const int p16 = tid & 15;

    const f4* Whh1T4  = (const f4*)(ws + OFF_WHH1T4);
    const float* Wih1T  = ws + OFF_WIH1T;
    const float* Wih2aT = ws + OFF_WIH2AT;
    const f4* Wih2bT4 = (const f4*)(ws + OFF_WIH2BT4);
    const f4* Whh2T4  = (const f4*)(ws + OFF_WHH2T4);
    const f4* oW1T4   = (const f4*)(ws + OFF_OW1T4);
    const f4* iW1T4   = (const f4*)(ws + OFF_IW1T4);
    const f4* ycur4   = (const f4*)(sm + L_YCUR);
    const f4* fw2l    = (const f4*)(sm + L_FW2);

    // register-cache fW1: rows 2kg, 2kg+1, cols 16p16..16p16+15 (8 f4 = 32 VGPR)
    f4 wz[2][4];
    {
        const f4* g = (const f4*)(ws + OFF_FW1R);
        #pragma unroll
        for (int r = 0; r < 2; ++r)
            #pragma unroll
            for (int m = 0; m < 4; ++m)
                wz[r][m] = g[(2 * kg + r) * 64 + p16 * 4 + m];
    }
    float fb1r[2];
    #pragma unroll
    for (int r = 0; r < 2; ++r) fb1r[r] = (2 * kg + r < 50) ? fb1[2 * kg + r] : 0.0f;

    const int yOwn = L_YCUR + yoffF(sh, i);   // own (state, comp) slot

    float y0 = 0.0f;   // own component of h[sh]
    __syncthreads();

    for (int t = 0; t < TT; ++t) {
        // ---- stage x and treat ----
        if (tid < 28) {
            sm[L_XA + tid] = (tid < 25) ? x[bg * (TT * 25) + t * 25 + tid] : 0.0f;
        }
        if (tid == 28) {
            const float* xp = x + bg * (TT * 25) + t * 25;
            sm[L_TR] = (xp[1] > 0.f || xp[2] > 0.f || xp[3] > 0.f || xp[4] > 0.f || xp[5] > 0.f) ? 1.0f : 0.0f;
        }
        const float sc = (dt[bg * (TT * 2) + t * 2 + 1] - dt[bg * (TT * 2) + t * 2]) * kDT_SC;
        __syncthreads();

        // ---- cell1 partial (split j-range by sh) ----
        {
            float acc = 0.0f;
            if (sh == 0) {
                acc = fmaf(Wih1T[i], sm[L_XA + 0], b1ci);
                #pragma unroll
                for (int j = 1; j < 19; ++j)
                    acc = fmaf(Wih1T[j * 256 + i], sm[L_XA + 6 + j], acc);
            }
            const int jb0 = sh * 32;
            f2 aL = {0.f, 0.f}, aH = {0.f, 0.f};
            #pragma unroll 4
            for (int jb = 0; jb < 32; ++jb) {
                f4 w = Whh1T4[(jb0 + jb) * 256 + i];
                f4 h = ycur4[yoff4(0, jb0 + jb)];
                pkfma(aL, vlo(w), vlo(h));
                pkfma(aH, vhi(w), vhi(h));
            }
            float part = acc + rsum2(aL + aH);
            sm[L_PART + sh * 256 + i] = part;
            __syncthreads();
            if (sh == 0) {   // combiner owns h_cov[i]
                y0 = y0 + fast_tanh(part + sm[L_PART + 256 + i]);
                sm[L_YCUR + yoffF(0, i)] = y0;
            }
        }
        __syncthreads();   // new h_cov visible

        // ---- cell2 partial (sh0: x-part + Wih2b·hc_new; sh1: Whh2·hi_old) ----
        {
            float acc = 0.0f;
            if (sh == 0) {
                acc = b2ci;
                #pragma unroll
                for (int j = 0; j < 5; ++j)
                    acc = fmaf(Wih2aT[j * 256 + i], sm[L_XA + 1 + j], acc);
            }
            const f4* Wp = sh ? Whh2T4 : Wih2bT4;
            f2 aL = {0.f, 0.f}, aH = {0.f, 0.f};
            #pragma unroll 4
            for (int jb = 0; jb < 64; ++jb) {
                f4 w = Wp[jb * 256 + i];
                f4 h = ycur4[yoff4(sh, jb)];   // sh0 reads new hc; sh1 reads old hi
                pkfma(aL, vlo(w), vlo(h));
                pkfma(aH, vhi(w), vhi(h));
            }
            float part = acc + rsum2(aL + aH);
            sm[L_PART + sh * 256 + i] = part;
            __syncthreads();
            if (sh == 1) {   // combiner owns h_ins[i]
                y0 = y0 + fast_tanh(sm[L_PART + i] + part);
                sm[L_YCUR + yoffF(1, i)] = y0;
            }
        }

        // ---- ODE: 8 RK4 steps ----
        for (int st = 0; st < NSTEP; ++st) {
            float acc_rk = 0.0f;
            #pragma unroll
            for (int e = 0; e < 4; ++e) {
                __syncthreads();   // ycur writes (cell publish / prev stage) visible
                // z-phase: rows 2kg, 2kg+1 x cols 16p16..+15, both states
                float pz[4];
                #pragma unroll
                for (int s = 0; s < 2; ++s) {
                    const f4* ys = ycur4 + s * 68 + (p16 >> 2) * 17 + (p16 & 3) * 4;
                    f2 P0l = {0,0}, P0h = {0,0}, P1l = {0,0}, P1h = {0,0};
                    #pragma unroll
                    for (int m = 0; m < 4; ++m) {
                        f4 y = ys[m];
                        f2 yl = vlo(y), yh = vhi(y);
                        pkfma(P0l, vlo(wz[0][m]), yl); pkfma(P0h, vhi(wz[0][m]), yh);
                        pkfma(P1l, vlo(wz[1][m]), yl); pkfma(P1h, vhi(wz[1][m]), yh);
                    }
                    pz[s * 2 + 0] = rsum2(P0l + P0h);
                    pz[s * 2 + 1] = rsum2(P1l + P1h);
                }
                #pragma unroll
                for (int r = 0; r < 4; ++r) pz[r] = allreduce16(pz[r]);
                if (p16 < 4) {
                    const int q = p16;
                    float a0 = (q & 1) ? pz[1] : pz[0];   // state0, row q&1
                    float a1 = (q & 1) ? pz[3] : pz[2];   // state1, row q&1
                    float vv = (q & 2) ? a1 : a0;
                    float fbs = (q & 1) ? fb1r[1] : fb1r[0];
                    sm[L_Z + (q >> 1) * 64 + 2 * kg + (q & 1)] = fast_tanh(vv + fbs);
                }
                __syncthreads();   // z ready
                // update: du for own (state sh, comp i)
                {
                    const f4* zv = (const f4*)(sm + L_Z + sh * 64);
                    f2 AL = {0,0}, AH = {0,0};
                    #pragma unroll
                    for (int kb = 0; kb < 13; ++kb) {
                        f4 w = fw2l[kb * 256 + i];
                        f4 z = zv[kb];
                        pkfma(AL, vlo(w), vlo(z));
                        pkfma(AH, vhi(w), vhi(z));
                    }
                    float du = (fb2i + rsum2(AL + AH)) * sc;
                    float yn;
                    if (e == 0) { acc_rk = du; yn = fmaf(0.5f * HS, du, y0); }
                    else if (e == 1) { acc_rk = fmaf(2.f, du, acc_rk); yn = fmaf(0.5f * HS, du, y0); }
                    else if (e == 2) { acc_rk = fmaf(2.f, du, acc_rk); yn = fmaf(HS, du, y0); }
                    else { acc_rk += du; y0 = fmaf(HS / 6.f, acc_rk, y0); yn = y0; }
                    sm[yOwn] = yn;
                }
            }
        }
        __syncthreads();   // final ycur (== h) visible

        // ---- output heads (head = sh) ----
        {
            const f4* Wh = sh ? iW1T4 : oW1T4;
            f2 aL = {0,0}, aH = {0,0};
            #pragma unroll 4
            for (int jb = 0; jb < 64; ++jb) {
                f4 w = Wh[jb * 256 + i];
                f4 h = ycur4[yoff4(sh, jb)];
                pkfma(aL, vlo(w), vlo(h));
                pkfma(aH, vhi(w), vhi(h));
            }
            float val = W2sel * fast_tanh(b1sel + rsum2(aL + aH));
            #pragma unroll
            for (int off = 32; off > 0; off >>= 1) val += __shfl_xor(val, off);
            if (lane == 0) sm[L_RED + wv] = val;
        }
        __syncthreads();
        if (tid == 0) {
            float co = sm[L_RED + 0] + sm[L_RED + 1] + sm[L_RED + 2] + sm[L_RED + 3] + ob2s;
            float ci = sm[L_RED + 4] + sm[L_RED + 5] + sm[L_RED + 6] + sm[L_RED + 7] + ib2s;
            out[bg * TT + t] = co - sm[L_TR] * fmaxf(ci, 0.0f);
        }
        __syncthreads();
    }
}

extern "C" void kernel_launch(void* const* d_in, const int* in_sizes, int n_in,
                              void* d_out, int out_size, void* d_ws, size_t ws_size,
                              hipStream_t stream) {
    const float* dt   = (const float*)d_in[0];
    const float* x    = (const float*)d_in[1];
    const float* Wih1 = (const float*)d_in[2];
    const float* Whh1 = (const float*)d_in[3];
    const float* bih1 = (const float*)d_in[4];
    const float* bhh1 = (const float*)d_in[5];
    const float* Wih2 = (const float*)d_in[6];
    const float* Whh2 = (const float*)d_in[7];
    const float* bih2 = (const float*)d_in[8];
    const float* bhh2 = (const float*)d_in[9];
    const float* oW1  = (const float*)d_in[10];
    const float* ob1  = (const float*)d_in[11];
    const float* oW2  = (const float*)d_in[12];
    const float* ob2  = (const float*)d_in[13];
    const float* iW1  = (const float*)d_in[14];
    const float* ib1  = (const float*)d_in[15];
    const float* iW2  = (const float*)d_in[16];
    const float* ib2  = (const float*)d_in[17];
    const float* fW1  = (const float*)d_in[18];
    const float* fb1  = (const float*)d_in[19];
    const float* fW2  = (const float*)d_in[20];
    const float* fb2  = (const float*)d_in[21];
    float* ws  = (float*)d_ws;
    float* out = (float*)d_out;

    if (ws_size < (size_t)WS_FLOATS * sizeof(float)) return;

    codernn_setup<<<WS_FLOATS / 256, 256, 0, stream>>>(Wih1, Whh1, bih1, bhh1, Wih2, Whh2,
                                                       bih2, bhh2, oW1, iW1, fW1, fW2, ws);

    codernn_main<<<512, 512, 0, stream>>>(dt, x, ws,
                                          ob1, oW2, ob2, ib1, iW2, ib2, fb1, fb2, out);
}

// Round 10
// 8011.196 us; speedup vs baseline: 2.1519x; 2.1519x over previous
//
#include <hip/hip_runtime.h>

// ---------------- problem constants ----------------
#define TT 100
#define NSTEP 8
__device__ __constant__ float kDT_SC = 1.0f / 24.0f;
#define HS (0.125f)

typedef float f4 __attribute__((ext_vector_type(4)));
typedef float f2 __attribute__((ext_vector_type(2)));

// ---------------- d_ws layout (floats) ----------------
#define OFF_WHH1T4   0         // [64][256][4]
#define OFF_WIH1T    65536     // [20][256]
#define OFF_WIH2AT   70656     // [8][256]
#define OFF_WIH2BT4  72704     // [64][256][4]
#define OFF_WHH2T4   138240    // [64][256][4]
#define OFF_OW1T4    203776    // [64][256][4]
#define OFF_IW1T4    269312    // [64][256][4]
#define OFF_FW1R     334848    // [64][256] row-major, zero-padded rows >= 50
#define OFF_FW2T4    351232    // [13][256][4]
#define OFF_B1C      364544    // [256] bih1+bhh1
#define OFF_B2C      364800    // [256] bih2+bhh2
#define WS_FLOATS    365056

// ---------------- LDS layout (floats) ----------------
#define L_YCUR  0        // 2 states * 272 (4 chunks of 68 = 64 data + 4 pad)
#define L_Z     544      // 2 states * 64
#define L_PART  672      // 256 (sh0 cell partials)
#define L_XA    928      // 28
#define L_TR    956      // 1
#define L_RED   957      // 8
#define L_TOTAL 965

__device__ __forceinline__ float fast_tanh(float v) {
    float e = __expf(2.0f * v);
    return 1.0f - 2.0f / (e + 1.0f);
}
__device__ __forceinline__ f2 vlo(f4 v) { return __builtin_shufflevector(v, v, 0, 1); }
__device__ __forceinline__ f2 vhi(f4 v) { return __builtin_shufflevector(v, v, 2, 3); }
// packed f32 fma (v_pk_fma_f32)
__device__ __forceinline__ void pkfma(f2& a, f2 w, f2 h) {
    a = __builtin_elementwise_fma(w, h, a);
}
__device__ __forceinline__ float rsum2(f2 a) { return a.x + a.y; }

// padded ycur indexing: state v has 4 chunks of 68 floats (64 data + 4 pad)
__device__ __forceinline__ int yoffF(int v, int j) { return v * 272 + (j >> 6) * 68 + (j & 63); }
__device__ __forceinline__ int yoff4(int v, int jb) { return v * 68 + (jb >> 4) * 17 + (jb & 15); }

// 16-lane allreduce via DPP rotate-add (row_ror:1,2,4,8)
template <int CTRL>
__device__ __forceinline__ float dpp_rr_add(float v) {
    int r = __builtin_amdgcn_update_dpp(0, __float_as_int(v), CTRL, 0xF, 0xF, false);
    return v + __int_as_float(r);
}
__device__ __forceinline__ float allreduce16(float v) {
    v = dpp_rr_add<0x121>(v);
    v = dpp_rr_add<0x122>(v);
    v = dpp_rr_add<0x124>(v);
    v = dpp_rr_add<0x128>(v);
    return v;
}

// ================= setup: repack weights into d_ws =================
__global__ void codernn_setup(const float* __restrict__ Wih1, const float* __restrict__ Whh1,
                              const float* __restrict__ bih1, const float* __restrict__ bhh1,
                              const float* __restrict__ Wih2, const float* __restrict__ Whh2,
                              const float* __restrict__ bih2, const float* __restrict__ bhh2,
                              const float* __restrict__ oW1, const float* __restrict__ iW1,
                              const float* __restrict__ fW1, const float* __restrict__ fW2,
                              float* __restrict__ ws) {
    int e = blockIdx.x * 256 + threadIdx.x;
    if (e >= WS_FLOATS) return;
    float v;
    if (e < OFF_WIH1T) {                 // Whh1T4
        int q = e; int jb = q >> 10, i = (q >> 2) & 255, dj = q & 3;
        v = Whh1[i * 256 + jb * 4 + dj];
    } else if (e < OFF_WIH2AT) {         // Wih1T [20][256]
        int q = e - OFF_WIH1T; int j = q >> 8, i = q & 255;
        v = (j < 19) ? Wih1[i * 19 + j] : 0.0f;
    } else if (e < OFF_WIH2BT4) {        // Wih2aT [8][256] (insulin cols 0..4)
        int q = e - OFF_WIH2AT; int j = q >> 8, i = q & 255;
        v = (j < 5) ? Wih2[i * 261 + j] : 0.0f;
    } else if (e < OFF_WHH2T4) {         // Wih2bT4 (cols 5..260)
        int q = e - OFF_WIH2BT4; int jb = q >> 10, i = (q >> 2) & 255, dj = q & 3;
        v = Wih2[i * 261 + 5 + jb * 4 + dj];
    } else if (e < OFF_OW1T4) {          // Whh2T4
        int q = e - OFF_WHH2T4; int jb = q >> 10, i = (q >> 2) & 255, dj = q & 3;
        v = Whh2[i * 256 + jb * 4 + dj];
    } else if (e < OFF_IW1T4) {          // oW1T4
        int q = e - OFF_OW1T4; int jb = q >> 10, i = (q >> 2) & 255, dj = q & 3;
        v = oW1[i * 256 + jb * 4 + dj];
    } else if (e < OFF_FW1R) {           // iW1T4
        int q = e - OFF_IW1T4; int jb = q >> 10, i = (q >> 2) & 255, dj = q & 3;
        v = iW1[i * 256 + jb * 4 + dj];
    } else if (e < OFF_FW2T4) {          // FW1R [64][256] row-major, zero-pad k>=50
        int q = e - OFF_FW1R; int k = q >> 8, j = q & 255;
        v = (k < 50) ? fW1[k * 256 + j] : 0.0f;
    } else if (e < OFF_B1C) {            // fW2T4 [13][256][4]: (kb*256+i)*4+dk = fW2[i][4kb+dk]
        int q = e - OFF_FW2T4; int kb = q >> 10, i = (q >> 2) & 255, dk = q & 3;
        int k = kb * 4 + dk;
        v = (k < 50) ? fW2[i * 50 + k] : 0.0f;
    } else if (e < OFF_B2C) {
        int q = e - OFF_B1C; v = bih1[q] + bhh1[q];
    } else {
        int q = e - OFF_B2C; v = bih2[q] + bhh2[q];
    }
    ws[e] = v;
}

// ================= main kernel =================
// 512 threads per batch element; 512 blocks; target 2 blocks/CU = 16 waves/CU.
// Waves 0-3 (sh=0): z-phase role, cache[] holds fW1 tile.
// Waves 4-7 (sh=1): update role (owns comp i of BOTH states), cache[] holds fW2 row.
__global__ __launch_bounds__(512, 2) void codernn_main(
    const float* __restrict__ dt, const float* __restrict__ x,
    const float* __restrict__ ws,
    const float* __restrict__ ob1, const float* __restrict__ oW2, const float* __restrict__ ob2,
    const float* __restrict__ ib1, const float* __restrict__ iW2, const float* __restrict__ ib2,
    const float* __restrict__ fb1, const float* __restrict__ fb2,
    float* __restrict__ out) {
    __shared__ float sm[L_TOTAL];
    const int tid = threadIdx.x;
    const int i = tid & 255;         // comp index for cell/update/output roles
    const int sh = tid >> 8;         // role half (wave-uniform)
    const int bg = blockIdx.x;
    const int lane = tid & 63, wv = tid >> 6;

    // zero ycur (incl. pads)
    for (int idx = tid; idx < 544; idx += 512) sm[L_YCUR + idx] = 0.0f;

    // per-thread constants
    const float b1ci = ws[OFF_B1C + i];
    const float b2ci = ws[OFF_B2C + i];
    const float fb2i = fb2[i];
    const float W2sel = sh ? iW2[i] : oW2[i];
    const float b1sel = sh ? ib1[i] : ob1[i];
    const float ob2s = ob2[0], ib2s = ib2[0];

    // z-phase thread mapping (valid for sh0 tids 0..255)
    const int kg = (tid >> 4) & 15;
    const int p16 = tid & 15;

    const f4* Whh1T4  = (const f4*)(ws + OFF_WHH1T4);
    const float* Wih1T  = ws + OFF_WIH1T;
    const float* Wih2aT = ws + OFF_WIH2AT;
    const f4* Wih2bT4 = (const f4*)(ws + OFF_WIH2BT4);
    const f4* Whh2T4  = (const f4*)(ws + OFF_WHH2T4);
    const f4* oW1T4   = (const f4*)(ws + OFF_OW1T4);
    const f4* iW1T4   = (const f4*)(ws + OFF_IW1T4);
    const f4* ycur4   = (const f4*)(sm + L_YCUR);

    // ---- role-dependent register cache (same 16 f4 = 64 VGPR for both roles) ----
    f4 cache[16];
    if (sh == 0) {
        // fW1 tile: rows 4kg..4kg+3, cols 16*p16..+15
        const f4* g = (const f4*)(ws + OFF_FW1R);
        #pragma unroll
        for (int r = 0; r < 4; ++r)
            #pragma unroll
            for (int m = 0; m < 4; ++m)
                cache[r * 4 + m] = g[(4 * kg + r) * 64 + p16 * 4 + m];
    } else {
        // fW2 row i (13 f4 over 52 padded k)
        const f4* g = (const f4*)(ws + OFF_FW2T4);
        #pragma unroll
        for (int kb = 0; kb < 13; ++kb)
            cache[kb] = g[kb * 256 + i];
        cache[13] = (f4){0,0,0,0}; cache[14] = (f4){0,0,0,0}; cache[15] = (f4){0,0,0,0};
    }
    float fb1r[4];
    #pragma unroll
    for (int r = 0; r < 4; ++r) fb1r[r] = (4 * kg + r < 50) ? fb1[4 * kg + r] : 0.0f;

    const int yA = L_YCUR + yoffF(0, i);   // comp i, cov state
    const int yB = L_YCUR + yoffF(1, i);   // comp i, ins state

    float y0a = 0.0f, y0b = 0.0f;   // owned by sh1 threads
    __syncthreads();

    for (int t = 0; t < TT; ++t) {
        // ---- stage x and treat ----
        if (tid < 28) {
            sm[L_XA + tid] = (tid < 25) ? x[bg * (TT * 25) + t * 25 + tid] : 0.0f;
        }
        if (tid == 28) {
            const float* xp = x + bg * (TT * 25) + t * 25;
            sm[L_TR] = (xp[1] > 0.f || xp[2] > 0.f || xp[3] > 0.f || xp[4] > 0.f || xp[5] > 0.f) ? 1.0f : 0.0f;
        }
        const float sc = (dt[bg * (TT * 2) + t * 2 + 1] - dt[bg * (TT * 2) + t * 2]) * kDT_SC;
        __syncthreads();

        // ---- cell1: split jb-range by sh; sh1 combines (owns y0a) ----
        float part;
        {
            float acc = 0.0f;
            if (sh == 0) {
                acc = fmaf(Wih1T[i], sm[L_XA + 0], b1ci);
                #pragma unroll
                for (int j = 1; j < 19; ++j)
                    acc = fmaf(Wih1T[j * 256 + i], sm[L_XA + 6 + j], acc);
            }
            const int jb0 = sh * 32;
            f2 aL = {0.f, 0.f}, aH = {0.f, 0.f};
            #pragma unroll 4
            for (int jb = 0; jb < 32; ++jb) {
                f4 w = Whh1T4[(jb0 + jb) * 256 + i];
                f4 h = ycur4[yoff4(0, jb0 + jb)];
                pkfma(aL, vlo(w), vlo(h));
                pkfma(aH, vhi(w), vhi(h));
            }
            part = acc + rsum2(aL + aH);
            if (sh == 0) sm[L_PART + i] = part;
        }
        __syncthreads();
        if (sh == 1) {
            y0a = y0a + fast_tanh(sm[L_PART + i] + part);
            sm[yA] = y0a;
        }
        __syncthreads();   // new h_cov visible

        // ---- cell2: sh0 = x-part + Wih2b·hc_new; sh1 = Whh2·hi_old; sh1 combines ----
        {
            float acc = 0.0f;
            if (sh == 0) {
                acc = b2ci;
                #pragma unroll
                for (int j = 0; j < 5; ++j)
                    acc = fmaf(Wih2aT[j * 256 + i], sm[L_XA + 1 + j], acc);
            }
            const f4* Wp = sh ? Whh2T4 : Wih2bT4;
            f2 aL = {0.f, 0.f}, aH = {0.f, 0.f};
            #pragma unroll 4
            for (int jb = 0; jb < 64; ++jb) {
                f4 w = Wp[jb * 256 + i];
                f4 h = ycur4[yoff4(sh, jb)];   // sh0: new hc; sh1: old hi
                pkfma(aL, vlo(w), vlo(h));
                pkfma(aH, vhi(w), vhi(h));
            }
            part = acc + rsum2(aL + aH);
            if (sh == 0) sm[L_PART + i] = part;
        }
        __syncthreads();
        if (sh == 1) {
            y0b = y0b + fast_tanh(sm[L_PART + i] + part);
            sm[yB] = y0b;
        }

        // ---- ODE: 8 RK4 steps; sh0 = z-phase, sh1 = update ----
        for (int st = 0; st < NSTEP; ++st) {
            float acca = 0.f, accb = 0.f;
            #pragma unroll
            for (int e = 0; e < 4; ++e) {
                __syncthreads();   // ycur writes (cell publish / prev stage) visible
                if (sh == 0) {
                    // z-phase: 4-row x 16-col fW1 tile, both states
                    float pz[8];
                    #pragma unroll
                    for (int s = 0; s < 2; ++s) {
                        const f4* ys = ycur4 + s * 68 + (p16 >> 2) * 17 + (p16 & 3) * 4;
                        f2 P0l = {0,0}, P0h = {0,0}, P1l = {0,0}, P1h = {0,0};
                        f2 P2l = {0,0}, P2h = {0,0}, P3l = {0,0}, P3h = {0,0};
                        #pragma unroll
                        for (int m = 0; m < 4; ++m) {
                            f4 y = ys[m];
                            f2 yl = vlo(y), yh = vhi(y);
                            pkfma(P0l, vlo(cache[m]), yl);      pkfma(P0h, vhi(cache[m]), yh);
                            pkfma(P1l, vlo(cache[4 + m]), yl);  pkfma(P1h, vhi(cache[4 + m]), yh);
                            pkfma(P2l, vlo(cache[8 + m]), yl);  pkfma(P2h, vhi(cache[8 + m]), yh);
                            pkfma(P3l, vlo(cache[12 + m]), yl); pkfma(P3h, vhi(cache[12 + m]), yh);
                        }
                        pz[s * 4 + 0] = rsum2(P0l + P0h);
                        pz[s * 4 + 1] = rsum2(P1l + P1h);
                        pz[s * 4 + 2] = rsum2(P2l + P2h);
                        pz[s * 4 + 3] = rsum2(P3l + P3h);
                    }
                    #pragma unroll
                    for (int r = 0; r < 8; ++r) pz[r] = allreduce16(pz[r]);
                    if (p16 < 8) {
                        const int q = p16;
                        float a0 = (q & 1) ? pz[1] : pz[0];
                        float a1 = (q & 1) ? pz[3] : pz[2];
                        float a2 = (q & 1) ? pz[5] : pz[4];
                        float a3 = (q & 1) ? pz[7] : pz[6];
                        float b0s = (q & 2) ? a1 : a0;
                        float b1s = (q & 2) ? a3 : a2;
                        float vsum = (q & 4) ? b1s : b0s;
                        float f0 = (q & 1) ? fb1r[1] : fb1r[0];
                        float f1 = (q & 1) ? fb1r[3] : fb1r[2];
                        float fb = (q & 2) ? f1 : f0;
                        sm[L_Z + (q >> 2) * 64 + 4 * kg + (q & 3)] = fast_tanh(vsum + fb);
                    }
                }
                __syncthreads();   // z ready
                if (sh == 1) {
                    // update: du for comp i of BOTH states; fW2 row in cache[]
                    const f4* zva = (const f4*)(sm + L_Z);
                    const f4* zvb = (const f4*)(sm + L_Z + 64);
                    f2 AL = {0,0}, AH = {0,0}, BL = {0,0}, BH = {0,0};
                    #pragma unroll
                    for (int kb = 0; kb < 13; ++kb) {
                        f4 w = cache[kb];
                        f4 za = zva[kb], zb = zvb[kb];
                        pkfma(AL, vlo(w), vlo(za)); pkfma(AH, vhi(w), vhi(za));
                        pkfma(BL, vlo(w), vlo(zb)); pkfma(BH, vhi(w), vhi(zb));
                    }
                    float dua = (fb2i + rsum2(AL + AH)) * sc;
                    float dub = (fb2i + rsum2(BL + BH)) * sc;
                    float ya, yb;
                    if (e == 0) {
                        acca = dua; accb = dub;
                        ya = fmaf(0.5f * HS, dua, y0a); yb = fmaf(0.5f * HS, dub, y0b);
                    } else if (e == 1) {
                        acca = fmaf(2.f, dua, acca); accb = fmaf(2.f, dub, accb);
                        ya = fmaf(0.5f * HS, dua, y0a); yb = fmaf(0.5f * HS, dub, y0b);
                    } else if (e == 2) {
                        acca = fmaf(2.f, dua, acca); accb = fmaf(2.f, dub, accb);
                        ya = fmaf(HS, dua, y0a); yb = fmaf(HS, dub, y0b);
                    } else {
                        acca += dua; accb += dub;
                        y0a = fmaf(HS / 6.f, acca, y0a); y0b = fmaf(HS / 6.f, accb, y0b);
                        ya = y0a; yb = y0b;
                    }
                    sm[yA] = ya;
                    sm[yB] = yb;
                }
            }
        }
        __syncthreads();   // final ycur (== h) visible

        // ---- output heads (head = sh), all threads active ----
        {
            const f4* Wh = sh ? iW1T4 : oW1T4;
            f2 aL = {0,0}, aH = {0,0};
            #pragma unroll 4
            for (int jb = 0; jb < 64; ++jb) {
                f4 w = Wh[jb * 256 + i];
                f4 h = ycur4[yoff4(sh, jb)];
                pkfma(aL, vlo(w), vlo(h));
                pkfma(aH, vhi(w), vhi(h));
            }
            float val = W2sel * fast_tanh(b1sel + rsum2(aL + aH));
            #pragma unroll
            for (int off = 32; off > 0; off >>= 1) val += __shfl_xor(val, off);
            if (lane == 0) sm[L_RED + wv] = val;
        }
        __syncthreads();
        if (tid == 0) {
            float co = sm[L_RED + 0] + sm[L_RED + 1] + sm[L_RED + 2] + sm[L_RED + 3] + ob2s;
            float ci = sm[L_RED + 4] + sm[L_RED + 5] + sm[L_RED + 6] + sm[L_RED + 7] + ib2s;
            out[bg * TT + t] = co - sm[L_TR] * fmaxf(ci, 0.0f);
        }
        __syncthreads();
    }
}

extern "C" void kernel_launch(void* const* d_in, const int* in_sizes, int n_in,
                              void* d_out, int out_size, void* d_ws, size_t ws_size,
                              hipStream_t stream) {
    const float* dt   = (const float*)d_in[0];
    const float* x    = (const float*)d_in[1];
    const float* Wih1 = (const float*)d_in[2];
    const float* Whh1 = (const float*)d_in[3];
    const float* bih1 = (const float*)d_in[4];
    const float* bhh1 = (const float*)d_in[5];
    const float* Wih2 = (const float*)d_in[6];
    const float* Whh2 = (const float*)d_in[7];
    const float* bih2 = (const float*)d_in[8];
    const float* bhh2 = (const float*)d_in[9];
    const float* oW1  = (const float*)d_in[10];
    const float* ob1  = (const float*)d_in[11];
    const float* oW2  = (const float*)d_in[12];
    const float* ob2  = (const float*)d_in[13];
    const float* iW1  = (const float*)d_in[14];
    const float* ib1  = (const float*)d_in[15];
    const float* iW2  = (const float*)d_in[16];
    const float* ib2  = (const float*)d_in[17];
    const float* fW1  = (const float*)d_in[18];
    const float* fb1  = (const float*)d_in[19];
    const float* fW2  = (const float*)d_in[20];
    const float* fb2  = (const float*)d_in[21];
    float* ws  = (float*)d_ws;
    float* out = (float*)d_out;

    if (ws_size < (size_t)WS_FLOATS * sizeof(float)) return;

    codernn_setup<<<WS_FLOATS / 256, 256, 0, stream>>>(Wih1, Whh1, bih1, bhh1, Wih2, Whh2,
                                                       bih2, bhh2, oW1, iW1, fW1, fW2, ws);

    codernn_main<<<512, 512, 0, stream>>>(dt, x, ws,
                                          ob1, oW2, ob2, ib1, iW2, ib2, fb1, fb2, out);
}

// Round 11
// 5273.241 us; speedup vs baseline: 3.2692x; 1.5192x over previous
//
#include <hip/hip_runtime.h>

// ---------------- problem constants ----------------
#define TT 100
#define NSTEP 8
__device__ __constant__ float kDT_SC = 1.0f / 24.0f;
#define HS (0.125f)

typedef float f4 __attribute__((ext_vector_type(4)));
typedef float f2 __attribute__((ext_vector_type(2)));

// ---------------- d_ws layout (floats) ----------------
#define OFF_WHH1T4   0         // [64][256][4]
#define OFF_WIH1T    65536     // [20][256]
#define OFF_WIH2AT   70656     // [8][256]
#define OFF_WIH2BT4  72704     // [64][256][4]
#define OFF_WHH2T4   138240    // [64][256][4]
#define OFF_OW1T4    203776    // [64][256][4]
#define OFF_IW1T4    269312    // [64][256][4]
#define OFF_FW1R     334848    // [64][256] row-major, zero-padded rows >= 50
#define OFF_FW2T4    351232    // [13][256][4]
#define OFF_B1C      364544    // [256] bih1+bhh1
#define OFF_B2C      364800    // [256] bih2+bhh2
#define WS_FLOATS    365056

// ---------------- LDS layout (floats) ----------------
// ycur: [2 el][2 state][272] (4 chunks of 68 = 64 data + 4 pad)
#define L_YC    0
#define L_Z     2176     // [2 el][2 state][64]
#define L_PART  2432     // [2 el][2 half][256]
#define L_XA    3456     // 2 * 28
#define L_TR    3512     // 2
#define L_RED   3514     // 16 (wv*2 + el)
#define L_TOTAL 3530

__device__ __forceinline__ float fast_tanh(float v) {
    float e = __expf(2.0f * v);
    return 1.0f - 2.0f / (e + 1.0f);
}
__device__ __forceinline__ f2 vlo(f4 v) { return __builtin_shufflevector(v, v, 0, 1); }
__device__ __forceinline__ f2 vhi(f4 v) { return __builtin_shufflevector(v, v, 2, 3); }
__device__ __forceinline__ void pkfma(f2& a, f2 w, f2 h) {
    a = __builtin_elementwise_fma(w, h, a);   // v_pk_fma_f32
}
__device__ __forceinline__ float rsum2(f2 a) { return a.x + a.y; }
// f4-unit index into one state's padded row
__device__ __forceinline__ int yi4(int jb) { return (jb >> 4) * 17 + (jb & 15); }

// 16-lane allreduce via DPP rotate-add (row_ror:1,2,4,8)
template <int CTRL>
__device__ __forceinline__ float dpp_rr_add(float v) {
    int r = __builtin_amdgcn_update_dpp(0, __float_as_int(v), CTRL, 0xF, 0xF, false);
    return v + __int_as_float(r);
}
__device__ __forceinline__ float allreduce16(float v) {
    v = dpp_rr_add<0x121>(v);
    v = dpp_rr_add<0x122>(v);
    v = dpp_rr_add<0x124>(v);
    v = dpp_rr_add<0x128>(v);
    return v;
}

// ================= setup: repack weights into d_ws =================
__global__ void codernn_setup(const float* __restrict__ Wih1, const float* __restrict__ Whh1,
                              const float* __restrict__ bih1, const float* __restrict__ bhh1,
                              const float* __restrict__ Wih2, const float* __restrict__ Whh2,
                              const float* __restrict__ bih2, const float* __restrict__ bhh2,
                              const float* __restrict__ oW1, const float* __restrict__ iW1,
                              const float* __restrict__ fW1, const float* __restrict__ fW2,
                              float* __restrict__ ws) {
    int e = blockIdx.x * 256 + threadIdx.x;
    if (e >= WS_FLOATS) return;
    float v;
    if (e < OFF_WIH1T) {                 // Whh1T4
        int q = e; int jb = q >> 10, i = (q >> 2) & 255, dj = q & 3;
        v = Whh1[i * 256 + jb * 4 + dj];
    } else if (e < OFF_WIH2AT) {         // Wih1T [20][256]
        int q = e - OFF_WIH1T; int j = q >> 8, i = q & 255;
        v = (j < 19) ? Wih1[i * 19 + j] : 0.0f;
    } else if (e < OFF_WIH2BT4) {        // Wih2aT [8][256] (insulin cols 0..4)
        int q = e - OFF_WIH2AT; int j = q >> 8, i = q & 255;
        v = (j < 5) ? Wih2[i * 261 + j] : 0.0f;
    } else if (e < OFF_WHH2T4) {         // Wih2bT4 (cols 5..260)
        int q = e - OFF_WIH2BT4; int jb = q >> 10, i = (q >> 2) & 255, dj = q & 3;
        v = Wih2[i * 261 + 5 + jb * 4 + dj];
    } else if (e < OFF_OW1T4) {          // Whh2T4
        int q = e - OFF_WHH2T4; int jb = q >> 10, i = (q >> 2) & 255, dj = q & 3;
        v = Whh2[i * 256 + jb * 4 + dj];
    } else if (e < OFF_IW1T4) {          // oW1T4
        int q = e - OFF_OW1T4; int jb = q >> 10, i = (q >> 2) & 255, dj = q & 3;
        v = oW1[i * 256 + jb * 4 + dj];
    } else if (e < OFF_FW1R) {           // iW1T4
        int q = e - OFF_IW1T4; int jb = q >> 10, i = (q >> 2) & 255, dj = q & 3;
        v = iW1[i * 256 + jb * 4 + dj];
    } else if (e < OFF_FW2T4) {          // FW1R [64][256] row-major, zero-pad k>=50
        int q = e - OFF_FW1R; int k = q >> 8, j = q & 255;
        v = (k < 50) ? fW1[k * 256 + j] : 0.0f;
    } else if (e < OFF_B1C) {            // fW2T4 [13][256][4]
        int q = e - OFF_FW2T4; int kb = q >> 10, i = (q >> 2) & 255, dk = q & 3;
        int k = kb * 4 + dk;
        v = (k < 50) ? fW2[i * 50 + k] : 0.0f;
    } else if (e < OFF_B2C) {
        int q = e - OFF_B1C; v = bih1[q] + bhh1[q];
    } else {
        int q = e - OFF_B2C; v = bih2[q] + bhh2[q];
    }
    ws[e] = v;
}

// z-phase for element EL (sh0 threads; uses cache[] = fW1 tile)
#define ZPHASE(EL) { \
    float pz[8]; \
    _Pragma("unroll") for (int s = 0; s < 2; ++s) { \
        const f4* ys = ycur4 + (EL) * 136 + s * 68 + (p16 >> 2) * 17 + (p16 & 3) * 4; \
        f2 P0l={0,0},P0h={0,0},P1l={0,0},P1h={0,0},P2l={0,0},P2h={0,0},P3l={0,0},P3h={0,0}; \
        _Pragma("unroll") for (int m = 0; m < 4; ++m) { \
            f4 y = ys[m]; f2 yl = vlo(y), yh = vhi(y); \
            pkfma(P0l, vlo(cache[m]), yl);      pkfma(P0h, vhi(cache[m]), yh); \
            pkfma(P1l, vlo(cache[4+m]), yl);    pkfma(P1h, vhi(cache[4+m]), yh); \
            pkfma(P2l, vlo(cache[8+m]), yl);    pkfma(P2h, vhi(cache[8+m]), yh); \
            pkfma(P3l, vlo(cache[12+m]), yl);   pkfma(P3h, vhi(cache[12+m]), yh); } \
        pz[s*4+0]=rsum2(P0l+P0h); pz[s*4+1]=rsum2(P1l+P1h); \
        pz[s*4+2]=rsum2(P2l+P2h); pz[s*4+3]=rsum2(P3l+P3h); } \
    _Pragma("unroll") for (int r = 0; r < 8; ++r) pz[r] = allreduce16(pz[r]); \
    if (p16 < 8) { const int q = p16; \
        float a0=(q&1)?pz[1]:pz[0]; float a1=(q&1)?pz[3]:pz[2]; \
        float a2=(q&1)?pz[5]:pz[4]; float a3=(q&1)?pz[7]:pz[6]; \
        float b0s=(q&2)?a1:a0; float b1s=(q&2)?a3:a2; float vsum=(q&4)?b1s:b0s; \
        float fz0=(q&1)?fb1r[1]:fb1r[0]; float fz1=(q&1)?fb1r[3]:fb1r[2]; float fb=(q&2)?fz1:fz0; \
        sm[L_Z + (EL)*128 + (q>>2)*64 + 4*kg + (q&3)] = fast_tanh(vsum + fb); } \
}

// RK4 update for element EL, stage SG (sh1 threads; cache[] = fW2 row i)
#define UPDATE(EL, SG, Y00, Y01, AC0, AC1, SCV) { \
    const f4* zva = (const f4*)(sm + L_Z + (EL) * 128); \
    const f4* zvb = zva + 16; \
    f2 AL={0,0},AH={0,0},BL={0,0},BH={0,0}; \
    _Pragma("unroll") for (int kb = 0; kb < 13; ++kb) { \
        f4 w = cache[kb]; f4 za = zva[kb], zb = zvb[kb]; \
        pkfma(AL, vlo(w), vlo(za)); pkfma(AH, vhi(w), vhi(za)); \
        pkfma(BL, vlo(w), vlo(zb)); pkfma(BH, vhi(w), vhi(zb)); } \
    float du0 = (fb2i + rsum2(AL + AH)) * (SCV); \
    float du1 = (fb2i + rsum2(BL + BH)) * (SCV); \
    float yn0, yn1; \
    if ((SG) == 0)      { AC0 = du0; AC1 = du1; yn0 = fmaf(0.5f*HS, du0, Y00); yn1 = fmaf(0.5f*HS, du1, Y01); } \
    else if ((SG) == 1) { AC0 = fmaf(2.f, du0, AC0); AC1 = fmaf(2.f, du1, AC1); yn0 = fmaf(0.5f*HS, du0, Y00); yn1 = fmaf(0.5f*HS, du1, Y01); } \
    else if ((SG) == 2) { AC0 = fmaf(2.f, du0, AC0); AC1 = fmaf(2.f, du1, AC1); yn0 = fmaf(HS, du0, Y00); yn1 = fmaf(HS, du1, Y01); } \
    else { AC0 += du0; AC1 += du1; Y00 = fmaf(HS/6.f, AC0, Y00); Y01 = fmaf(HS/6.f, AC1, Y01); yn0 = Y00; yn1 = Y01; } \
    sm[L_YC + (EL)*544 + yslot] = yn0; \
    sm[L_YC + (EL)*544 + 272 + yslot] = yn1; \
}

// ================= main kernel =================
// 256 blocks x 512 threads; 2 batch elements per block (A, B); 1 block/CU.
// sh0 waves: z-phase role (cache = fW1 tile). sh1 waves: update role (cache = fW2 row).
// ODE software pipeline: phase = { z(X) || update(Y) }, X != Y, 1 barrier each.
__global__ __launch_bounds__(512, 2) void codernn_main(
    const float* __restrict__ dt, const float* __restrict__ x,
    const float* __restrict__ ws,
    const float* __restrict__ ob1, const float* __restrict__ oW2, const float* __restrict__ ob2,
    const float* __restrict__ ib1, const float* __restrict__ iW2, const float* __restrict__ ib2,
    const float* __restrict__ fb1, const float* __restrict__ fb2,
    float* __restrict__ out) {
    __shared__ float sm[L_TOTAL];
    const int tid = threadIdx.x;
    const int i = tid & 255;
    const int sh = tid >> 8;               // wave-uniform role bit
    const int bgA = blockIdx.x * 2, bgB = bgA + 1;
    const int lane = tid & 63, wv = tid >> 6;
    const int kg = (tid >> 4) & 15;
    const int p16 = tid & 15;

    for (int idx = tid; idx < 1088; idx += 512) sm[L_YC + idx] = 0.0f;

    const float b1ci = ws[OFF_B1C + i];
    const float b2ci = ws[OFF_B2C + i];
    const float fb2i = fb2[i];
    const float W2sel = sh ? iW2[i] : oW2[i];
    const float b1sel = sh ? ib1[i] : ob1[i];
    const float ob2s = ob2[0], ib2s = ib2[0];

    const f4* Whh1T4  = (const f4*)(ws + OFF_WHH1T4);
    const float* Wih1T  = ws + OFF_WIH1T;
    const float* Wih2aT = ws + OFF_WIH2AT;
    const f4* Wih2bT4 = (const f4*)(ws + OFF_WIH2BT4);
    const f4* Whh2T4  = (const f4*)(ws + OFF_WHH2T4);
    const f4* oW1T4   = (const f4*)(ws + OFF_OW1T4);
    const f4* iW1T4   = (const f4*)(ws + OFF_IW1T4);
    const f4* ycur4   = (const f4*)(sm + L_YC);

    // role-dependent register cache (16 f4)
    f4 cache[16];
    if (sh == 0) {
        const f4* g = (const f4*)(ws + OFF_FW1R);
        #pragma unroll
        for (int r = 0; r < 4; ++r)
            #pragma unroll
            for (int m = 0; m < 4; ++m)
                cache[r * 4 + m] = g[(4 * kg + r) * 64 + p16 * 4 + m];
    } else {
        const f4* g = (const f4*)(ws + OFF_FW2T4);
        #pragma unroll
        for (int kb = 0; kb < 13; ++kb) cache[kb] = g[kb * 256 + i];
        cache[13] = (f4){0,0,0,0}; cache[14] = (f4){0,0,0,0}; cache[15] = (f4){0,0,0,0};
    }
    float fb1r[4];
    #pragma unroll
    for (int r = 0; r < 4; ++r) fb1r[r] = (4 * kg + r < 50) ? fb1[4 * kg + r] : 0.0f;

    const int yslot = (i >> 6) * 68 + (i & 63);   // float offset within one state row

    // h masters (meaningful on sh1 threads only)
    float y0A0 = 0.f, y0A1 = 0.f, y0B0 = 0.f, y0B1 = 0.f;
    float accA0, accA1, accB0, accB1;
    __syncthreads();

    for (int t = 0; t < TT; ++t) {
        // ---- stage x, treat ----
        if (tid < 56) {
            int bb = tid / 28, c = tid - bb * 28;
            const float* xp = x + (bgA + bb) * (TT * 25) + t * 25;
            sm[L_XA + tid] = (c < 25) ? xp[c] : 0.0f;
            if (c == 25)
                sm[L_TR + bb] = (xp[1] > 0.f || xp[2] > 0.f || xp[3] > 0.f || xp[4] > 0.f || xp[5] > 0.f) ? 1.0f : 0.0f;
        }
        const float scA = (dt[bgA * (TT * 2) + t * 2 + 1] - dt[bgA * (TT * 2) + t * 2]) * kDT_SC;
        const float scB = (dt[bgB * (TT * 2) + t * 2 + 1] - dt[bgB * (TT * 2) + t * 2]) * kDT_SC;
        __syncthreads();

        // ---- cell1: shared weight stream, both elements; jb-range split by sh ----
        {
            float xpA = 0.f, xpB = 0.f;
            if (sh == 0) {
                xpA = fmaf(Wih1T[i], sm[L_XA + 0], b1ci);
                xpB = fmaf(Wih1T[i], sm[L_XA + 28 + 0], b1ci);
                #pragma unroll
                for (int j = 1; j < 19; ++j) {
                    float w = Wih1T[j * 256 + i];
                    xpA = fmaf(w, sm[L_XA + 6 + j], xpA);
                    xpB = fmaf(w, sm[L_XA + 28 + 6 + j], xpB);
                }
            }
            const int jb0 = sh * 32;
            f2 aLA={0,0},aHA={0,0},aLB={0,0},aHB={0,0};
            #pragma unroll 4
            for (int jb = 0; jb < 32; ++jb) {
                f4 w = Whh1T4[(jb0 + jb) * 256 + i];
                f4 hA = ycur4[yi4(jb0 + jb)];             // el A, state 0
                f4 hB = ycur4[136 + yi4(jb0 + jb)];       // el B, state 0
                pkfma(aLA, vlo(w), vlo(hA)); pkfma(aHA, vhi(w), vhi(hA));
                pkfma(aLB, vlo(w), vlo(hB)); pkfma(aHB, vhi(w), vhi(hB));
            }
            sm[L_PART + sh * 256 + i] = xpA + rsum2(aLA + aHA);
            sm[L_PART + 512 + sh * 256 + i] = xpB + rsum2(aLB + aHB);
        }
        __syncthreads();
        if (sh == 1) {
            y0A0 = y0A0 + fast_tanh(sm[L_PART + i] + sm[L_PART + 256 + i]);
            sm[L_YC + yslot] = y0A0;
            y0B0 = y0B0 + fast_tanh(sm[L_PART + 512 + i] + sm[L_PART + 768 + i]);
            sm[L_YC + 544 + yslot] = y0B0;
        }
        __syncthreads();

        // ---- cell2: sh0 = x-part + Wih2b*hc_new; sh1 = Whh2*hi_old; both elements ----
        {
            float xpA = 0.f, xpB = 0.f;
            if (sh == 0) {
                xpA = b2ci; xpB = b2ci;
                #pragma unroll
                for (int j = 0; j < 5; ++j) {
                    float w = Wih2aT[j * 256 + i];
                    xpA = fmaf(w, sm[L_XA + 1 + j], xpA);
                    xpB = fmaf(w, sm[L_XA + 28 + 1 + j], xpB);
                }
            }
            const f4* Wp = sh ? Whh2T4 : Wih2bT4;
            const int stsel = sh;   // sh0 reads new hc (st0), sh1 reads old hi (st1)
            f2 aLA={0,0},aHA={0,0},aLB={0,0},aHB={0,0};
            #pragma unroll 4
            for (int jb = 0; jb < 64; ++jb) {
                f4 w = Wp[jb * 256 + i];
                f4 hA = ycur4[stsel * 68 + yi4(jb)];
                f4 hB = ycur4[136 + stsel * 68 + yi4(jb)];
                pkfma(aLA, vlo(w), vlo(hA)); pkfma(aHA, vhi(w), vhi(hA));
                pkfma(aLB, vlo(w), vlo(hB)); pkfma(aHB, vhi(w), vhi(hB));
            }
            sm[L_PART + sh * 256 + i] = xpA + rsum2(aLA + aHA);
            sm[L_PART + 512 + sh * 256 + i] = xpB + rsum2(aLB + aHB);
        }
        __syncthreads();
        if (sh == 1) {
            y0A1 = y0A1 + fast_tanh(sm[L_PART + i] + sm[L_PART + 256 + i]);
            sm[L_YC + 272 + yslot] = y0A1;
            y0B1 = y0B1 + fast_tanh(sm[L_PART + 512 + i] + sm[L_PART + 768 + i]);
            sm[L_YC + 544 + 272 + yslot] = y0B1;
        }
        __syncthreads();

        // ---- ODE: software-pipelined; 65 phases per timestep ----
        if (sh == 0) ZPHASE(0);          // prologue: z_A(0)
        __syncthreads();
        for (int st = 0; st < NSTEP; ++st) {
            #pragma unroll
            for (int sg = 0; sg < 4; ++sg) {
                // phase: z_B(e) || upd_A(e)
                if (sh == 0) { ZPHASE(1); }
                else         { UPDATE(0, sg, y0A0, y0A1, accA0, accA1, scA); }
                __syncthreads();
                // phase: z_A(e+1) || upd_B(e)   (final z_A(32) is harmless)
                if (sh == 0) { ZPHASE(0); }
                else         { UPDATE(1, sg, y0B0, y0B1, accB0, accB1, scB); }
                __syncthreads();
            }
        }

        // ---- output heads: head = sh (o reads st0, i reads st1); both elements ----
        {
            const f4* Wh = sh ? iW1T4 : oW1T4;
            const int stsel = sh;
            f2 aLA={0,0},aHA={0,0},aLB={0,0},aHB={0,0};
            #pragma unroll 4
            for (int jb = 0; jb < 64; ++jb) {
                f4 w = Wh[jb * 256 + i];
                f4 hA = ycur4[stsel * 68 + yi4(jb)];
                f4 hB = ycur4[136 + stsel * 68 + yi4(jb)];
                pkfma(aLA, vlo(w), vlo(hA)); pkfma(aHA, vhi(w), vhi(hA));
                pkfma(aLB, vlo(w), vlo(hB)); pkfma(aHB, vhi(w), vhi(hB));
            }
            float vA = W2sel * fast_tanh(b1sel + rsum2(aLA + aHA));
            float vB = W2sel * fast_tanh(b1sel + rsum2(aLB + aHB));
            #pragma unroll
            for (int off = 32; off > 0; off >>= 1) {
                vA += __shfl_xor(vA, off);
                vB += __shfl_xor(vB, off);
            }
            if (lane == 0) { sm[L_RED + wv * 2] = vA; sm[L_RED + wv * 2 + 1] = vB; }
        }
        __syncthreads();
        if (tid == 0) {
            float coA = sm[L_RED + 0] + sm[L_RED + 2] + sm[L_RED + 4] + sm[L_RED + 6] + ob2s;
            float ciA = sm[L_RED + 8] + sm[L_RED + 10] + sm[L_RED + 12] + sm[L_RED + 14] + ib2s;
            out[bgA * TT + t] = coA - sm[L_TR] * fmaxf(ciA, 0.0f);
            float coB = sm[L_RED + 1] + sm[L_RED + 3] + sm[L_RED + 5] + sm[L_RED + 7] + ob2s;
            float ciB = sm[L_RED + 9] + sm[L_RED + 11] + sm[L_RED + 13] + sm[L_RED + 15] + ib2s;
            out[bgB * TT + t] = coB - sm[L_TR + 1] * fmaxf(ciB, 0.0f);
        }
        __syncthreads();
    }
}

extern "C" void kernel_launch(void* const* d_in, const int* in_sizes, int n_in,
                              void* d_out, int out_size, void* d_ws, size_t ws_size,
                              hipStream_t stream) {
    const float* dt   = (const float*)d_in[0];
    const float* x    = (const float*)d_in[1];
    const float* Wih1 = (const float*)d_in[2];
    const float* Whh1 = (const float*)d_in[3];
    const float* bih1 = (const float*)d_in[4];
    const float* bhh1 = (const float*)d_in[5];
    const float* Wih2 = (const float*)d_in[6];
    const float* Whh2 = (const float*)d_in[7];
    const float* bih2 = (const float*)d_in[8];
    const float* bhh2 = (const float*)d_in[9];
    const float* oW1  = (const float*)d_in[10];
    const float* ob1  = (const float*)d_in[11];
    const float* oW2  = (const float*)d_in[12];
    const float* ob2  = (const float*)d_in[13];
    const float* iW1  = (const float*)d_in[14];
    const float* ib1  = (const float*)d_in[15];
    const float* iW2  = (const float*)d_in[16];
    const float* ib2  = (const float*)d_in[17];
    const float* fW1  = (const float*)d_in[18];
    const float* fb1  = (const float*)d_in[19];
    const float* fW2  = (const float*)d_in[20];
    const float* fb2  = (const float*)d_in[21];
    float* ws  = (float*)d_ws;
    float* out = (float*)d_out;

    if (ws_size < (size_t)WS_FLOATS * sizeof(float)) return;

    codernn_setup<<<WS_FLOATS / 256, 256, 0, stream>>>(Wih1, Whh1, bih1, bhh1, Wih2, Whh2,
                                                       bih2, bhh2, oW1, iW1, fW1, fW2, ws);

    codernn_main<<<256, 512, 0, stream>>>(dt, x, ws,
                                          ob1, oW2, ob2, ib1, iW2, ib2, fb1, fb2, out);
}